// Round 7
// baseline (317.077 us; speedup 1.0000x reference)
//
#include <hip/hip_runtime.h>
#include <hip/hip_fp16.h>

#define SLOPE 0.2f

__device__ __forceinline__ float lrelu(float v) { return v >= 0.f ? v : SLOPE * v; }

__device__ __forceinline__ unsigned pack2(float a, float b) {
    __half2 h = __floats2half2_rn(a, b);
    return *reinterpret_cast<unsigned*>(&h);
}
__device__ __forceinline__ float2 h2f(unsigned u) {
    __half2 h = *reinterpret_cast<__half2*>(&u);
    return __half22float2(h);
}

// 8 half elements (uint4) scaled by packed-half2 'ap', accumulated into
// 4 packed fp16 pairs via v_pk_fma_f16 (1 inst per 2 halves — R20).
// Per-lane fp16 partials only span ~1.5 edges; cross-edge sum stays f32.
__device__ __forceinline__ void pk8(unsigned& A0, unsigned& A1, unsigned& A2, unsigned& A3,
                                    unsigned ap, uint4 u) {
    __half2 a = *reinterpret_cast<__half2*>(&ap);
    __half2* up = reinterpret_cast<__half2*>(&u);
    *reinterpret_cast<__half2*>(&A0) = __hfma2(up[0], a, *reinterpret_cast<__half2*>(&A0));
    *reinterpret_cast<__half2*>(&A1) = __hfma2(up[1], a, *reinterpret_cast<__half2*>(&A1));
    *reinterpret_cast<__half2*>(&A2) = __hfma2(up[2], a, *reinterpret_cast<__half2*>(&A2));
    *reinterpret_cast<__half2*>(&A3) = __hfma2(up[3], a, *reinterpret_cast<__half2*>(&A3));
}

// ============================================================================
// xp = h @ W (64 -> 128 = 2 heads * 64) + attention dots, block-tile GEMM.
// Input h is fp16 (written by k_ag). 64 nodes/block, 256 threads.
// ============================================================================
__global__ __launch_bounds__(256)
void k_xp_gemm64h(const __half* __restrict__ x, const float* __restrict__ W,
                  const float* __restrict__ as_, const float* __restrict__ ad_,
                  __half* __restrict__ xph, float* __restrict__ asrc,
                  float* __restrict__ adst, int N) {
    constexpr int K = 64;
    constexpr int ZS = K + 1;
    __shared__ float zs[64 * ZS];
    __shared__ float ws[K * 128];
    const int n0 = blockIdx.x * 64;
    const int t = threadIdx.x;

    for (int i = t; i < K * 32; i += 256) ((float4*)ws)[i] = ((const float4*)W)[i];
    for (int i = t; i < 64 * 8; i += 256) {          // 8 x uint4 (8 halfs) per row
        int n = i >> 3, k8 = i & 7;
        int gn = n0 + n;
        uint4 v = make_uint4(0u, 0u, 0u, 0u);
        if (gn < N) v = ((const uint4*)x)[(size_t)gn * 8 + k8];
        float2 f0 = h2f(v.x), f1 = h2f(v.y), f2 = h2f(v.z), f3 = h2f(v.w);
        float* zr = zs + n * ZS + k8 * 8;
        zr[0] = f0.x; zr[1] = f0.y; zr[2] = f1.x; zr[3] = f1.y;
        zr[4] = f2.x; zr[5] = f2.y; zr[6] = f3.x; zr[7] = f3.y;
    }
    __syncthreads();

    const int tx = t & 15, ty = t >> 4;
    const int c0a = tx * 4;
    const int c0b = 64 + tx * 4;

    float4 asA = *(const float4*)(as_ + c0a);
    float4 asB = *(const float4*)(as_ + c0b);
    float4 adA = *(const float4*)(ad_ + c0a);
    float4 adB = *(const float4*)(ad_ + c0b);

    float acc[4][8];
    #pragma unroll
    for (int i = 0; i < 4; ++i)
        #pragma unroll
        for (int j = 0; j < 8; ++j) acc[i][j] = 0.f;

    for (int k = 0; k < K; ++k) {
        float4 w0 = *(const float4*)(ws + k * 128 + c0a);
        float4 w1 = *(const float4*)(ws + k * 128 + c0b);
        #pragma unroll
        for (int i = 0; i < 4; ++i) {
            float zv = zs[(ty * 4 + i) * ZS + k];
            acc[i][0] += zv * w0.x; acc[i][1] += zv * w0.y;
            acc[i][2] += zv * w0.z; acc[i][3] += zv * w0.w;
            acc[i][4] += zv * w1.x; acc[i][5] += zv * w1.y;
            acc[i][6] += zv * w1.z; acc[i][7] += zv * w1.w;
        }
    }

    #pragma unroll
    for (int i = 0; i < 4; ++i) {
        int nl = ty * 4 + i, gn = n0 + nl;
        if (gn < N) {
            uint2 ua, ub;
            ua.x = pack2(acc[i][0], acc[i][1]);
            ua.y = pack2(acc[i][2], acc[i][3]);
            ub.x = pack2(acc[i][4], acc[i][5]);
            ub.y = pack2(acc[i][6], acc[i][7]);
            *(uint2*)(xph + (size_t)gn * 128 + c0a) = ua;
            *(uint2*)(xph + (size_t)gn * 128 + c0b) = ub;
        }
        float ps0 = acc[i][0]*asA.x + acc[i][1]*asA.y + acc[i][2]*asA.z + acc[i][3]*asA.w;
        float ps1 = acc[i][4]*asB.x + acc[i][5]*asB.y + acc[i][6]*asB.z + acc[i][7]*asB.w;
        float pd0 = acc[i][0]*adA.x + acc[i][1]*adA.y + acc[i][2]*adA.z + acc[i][3]*adA.w;
        float pd1 = acc[i][4]*adB.x + acc[i][5]*adB.y + acc[i][6]*adB.z + acc[i][7]*adB.w;
        #pragma unroll
        for (int off = 1; off <= 8; off <<= 1) {
            ps0 += __shfl_xor(ps0, off, 64);
            ps1 += __shfl_xor(ps1, off, 64);
            pd0 += __shfl_xor(pd0, off, 64);
            pd1 += __shfl_xor(pd1, off, 64);
        }
        if (tx == 0 && gn < N) {
            asrc[gn * 2]     = ps0;
            asrc[gn * 2 + 1] = ps1;
            adst[gn * 2]     = pd0;
            adst[gn * 2 + 1] = pd1;
        }
    }
}

// ============================================================================
// CSR build: histogram with rank capture, ILP-4 (R19).
// NOTE (R18): cursor-based scatter (atomic->dependent store) is 74us — never
// couple the scatter store to an atomic result.
// ============================================================================
__global__ void k_hist(const int* __restrict__ dst, int* __restrict__ deg,
                       int* __restrict__ rank, int E) {
    int e0 = (blockIdx.x * blockDim.x + threadIdx.x) * 4;
    if (e0 + 3 < E) {
        int4 d = *(const int4*)(dst + e0);
        int r0 = atomicAdd(&deg[d.x], 1);
        int r1 = atomicAdd(&deg[d.y], 1);
        int r2 = atomicAdd(&deg[d.z], 1);
        int r3 = atomicAdd(&deg[d.w], 1);
        *(int4*)(rank + e0) = make_int4(r0, r1, r2, r3);
    } else {
        for (int e = e0; e < E; ++e) rank[e] = atomicAdd(&deg[dst[e]], 1);
    }
}

__global__ void k_scan_partial(const int* __restrict__ deg, int* __restrict__ partial, int N) {
    int b = blockIdx.x, t = threadIdx.x;
    int base = b * 1024 + t * 4;
    int s = 0;
    for (int i = 0; i < 4; ++i) { int idx = base + i; if (idx < N) s += deg[idx]; }
    __shared__ int sh[256];
    sh[t] = s; __syncthreads();
    for (int off = 128; off > 0; off >>= 1) { if (t < off) sh[t] += sh[t + off]; __syncthreads(); }
    if (t == 0) partial[b] = sh[0];
}

__global__ void k_scan_final(const int* __restrict__ deg, const int* __restrict__ partial,
                             int* __restrict__ rowptr, int N, int E, int nb) {
    int b = blockIdx.x, t = threadIdx.x;
    __shared__ int shp[256];
    shp[t] = (t < nb) ? partial[t] : 0;
    __syncthreads();
    for (int off = 1; off < 256; off <<= 1) {
        int v = (t >= off) ? shp[t - off] : 0;
        __syncthreads();
        shp[t] += v;
        __syncthreads();
    }
    int pbase = (b > 0) ? shp[b - 1] : 0;
    __syncthreads();

    int base = b * 1024 + t * 4;
    int local[4]; int s = 0;
    for (int i = 0; i < 4; ++i) { int idx = base + i; local[i] = (idx < N) ? deg[idx] : 0; s += local[i]; }
    __shared__ int sh[256];
    int orig = s;
    sh[t] = s; __syncthreads();
    for (int off = 1; off < 256; off <<= 1) {
        int v = (t >= off) ? sh[t - off] : 0;
        __syncthreads();
        sh[t] += v;
        __syncthreads();
    }
    int run = pbase + sh[t] - orig;
    for (int i = 0; i < 4; ++i) {
        int idx = base + i;
        if (idx < N) rowptr[idx] = run;
        run += local[i];
    }
    if (b == 0 && t == 0) rowptr[N] = E;
}

// ============================================================================
// FUSED independent work after scan_final, branched on blockIdx range:
//   [0, nEdgeBlk4)               -> csr scatter, ILP-4 (rank-based, R19)
//   [nEdgeBlk4, +nTile)          -> xp_gemm K=6 (layer-1 projection)
//   [.., +nClimber)              -> climber embed + cpre
// ============================================================================
__global__ __launch_bounds__(256)
void k_fused3(const int* __restrict__ srcI, const int* __restrict__ dstI,
              const int* __restrict__ rowptr, const int* __restrict__ rank,
              int* __restrict__ csr_src, int E,
              const float* __restrict__ x, const float* __restrict__ W1,
              const float* __restrict__ as1, const float* __restrict__ ad1,
              __half* __restrict__ xph, float* __restrict__ asrc,
              float* __restrict__ adst, int N,
              const float* __restrict__ climber, const float* __restrict__ Wc,
              const float* __restrict__ bc, const float* __restrict__ Wm1,
              const float* __restrict__ bm1, float* __restrict__ cpre, int G,
              int nEdgeBlk4, int nTile) {
    __shared__ float smem[4352];        // max(climber 4352, gemm6 1216) floats
    int bid = blockIdx.x;
    const int t = threadIdx.x;

    if (bid < nEdgeBlk4) {
        // ---- csr scatter, 4 edges/thread: independent gathers + stores ----
        int e0 = (bid * 256 + t) * 4;
        if (e0 + 3 < E) {
            int4 s = *(const int4*)(srcI + e0);
            int4 d = *(const int4*)(dstI + e0);
            int4 r = *(const int4*)(rank + e0);
            int p0 = rowptr[d.x] + r.x;
            int p1 = rowptr[d.y] + r.y;
            int p2 = rowptr[d.z] + r.z;
            int p3 = rowptr[d.w] + r.w;
            csr_src[p0] = s.x;
            csr_src[p1] = s.y;
            csr_src[p2] = s.z;
            csr_src[p3] = s.w;
        } else {
            for (int e = e0; e < E; ++e)
                csr_src[rowptr[dstI[e]] + rank[e]] = srcI[e];
        }
        return;
    }
    bid -= nEdgeBlk4;
    if (bid < nTile) {
        // ---- xp_gemm K=6 ----
        constexpr int K = 6, ZS = 7;
        float* zs = smem;               // 64*7  = 448
        float* ws = smem + 448;         // 6*128 = 768 (offset 1792 B, 16B-aligned)
        const int n0 = bid * 64;

        for (int i = t; i < K * 32; i += 256) ((float4*)ws)[i] = ((const float4*)W1)[i];
        for (int i = t; i < 64 * K; i += 256) {
            int n = i / K, k = i - n * K;
            int gn = n0 + n;
            zs[n * ZS + k] = (gn < N) ? x[(size_t)gn * K + k] : 0.f;
        }
        __syncthreads();

        const int tx = t & 15, ty = t >> 4;
        const int c0a = tx * 4;
        const int c0b = 64 + tx * 4;

        float4 asA = *(const float4*)(as1 + c0a);
        float4 asB = *(const float4*)(as1 + c0b);
        float4 adA = *(const float4*)(ad1 + c0a);
        float4 adB = *(const float4*)(ad1 + c0b);

        float acc[4][8];
        #pragma unroll
        for (int i = 0; i < 4; ++i)
            #pragma unroll
            for (int j = 0; j < 8; ++j) acc[i][j] = 0.f;

        for (int k = 0; k < K; ++k) {
            float4 w0 = *(const float4*)(ws + k * 128 + c0a);
            float4 w1 = *(const float4*)(ws + k * 128 + c0b);
            #pragma unroll
            for (int i = 0; i < 4; ++i) {
                float zv = zs[(ty * 4 + i) * ZS + k];
                acc[i][0] += zv * w0.x; acc[i][1] += zv * w0.y;
                acc[i][2] += zv * w0.z; acc[i][3] += zv * w0.w;
                acc[i][4] += zv * w1.x; acc[i][5] += zv * w1.y;
                acc[i][6] += zv * w1.z; acc[i][7] += zv * w1.w;
            }
        }

        #pragma unroll
        for (int i = 0; i < 4; ++i) {
            int nl = ty * 4 + i, gn = n0 + nl;
            if (gn < N) {
                uint2 ua, ub;
                ua.x = pack2(acc[i][0], acc[i][1]);
                ua.y = pack2(acc[i][2], acc[i][3]);
                ub.x = pack2(acc[i][4], acc[i][5]);
                ub.y = pack2(acc[i][6], acc[i][7]);
                *(uint2*)(xph + (size_t)gn * 128 + c0a) = ua;
                *(uint2*)(xph + (size_t)gn * 128 + c0b) = ub;
            }
            float ps0 = acc[i][0]*asA.x + acc[i][1]*asA.y + acc[i][2]*asA.z + acc[i][3]*asA.w;
            float ps1 = acc[i][4]*asB.x + acc[i][5]*asB.y + acc[i][6]*asB.z + acc[i][7]*asB.w;
            float pd0 = acc[i][0]*adA.x + acc[i][1]*adA.y + acc[i][2]*adA.z + acc[i][3]*adA.w;
            float pd1 = acc[i][4]*adB.x + acc[i][5]*adB.y + acc[i][6]*adB.z + acc[i][7]*adB.w;
            #pragma unroll
            for (int off = 1; off <= 8; off <<= 1) {
                ps0 += __shfl_xor(ps0, off, 64);
                ps1 += __shfl_xor(ps1, off, 64);
                pd0 += __shfl_xor(pd0, off, 64);
                pd1 += __shfl_xor(pd1, off, 64);
            }
            if (tx == 0 && gn < N) {
                asrc[gn * 2]     = ps0;
                asrc[gn * 2 + 1] = ps1;
                adst[gn * 2]     = pd0;
                adst[gn * 2 + 1] = pd1;
            }
        }
        return;
    }
    bid -= nTile;
    {
        // ---- climber embed + cpre ----
        float* ce   = smem;             // 4*64
        float* wm1b = smem + 256;       // 64*64
        for (int i = t; i < 1024; i += 256) ((float4*)wm1b)[i] = ((const float4*)Wm1)[1024 + i];
        int gl = t >> 6, c = t & 63;
        int g = bid * 4 + gl;
        float acc = bc[c];
        if (g < G)
            for (int k = 0; k < 4; ++k) acc += climber[g * 4 + k] * Wc[k * 64 + c];
        ce[gl * 64 + c] = fmaxf(acc, 0.f);
        __syncthreads();
        float o = bm1[c];
        for (int k = 0; k < 64; ++k) o += ce[gl * 64 + k] * wm1b[k * 64 + c];
        if (g < G) cpre[(size_t)g * 64 + c] = o;
    }
}

// ============================================================================
// FUSED softmax + gather (R1 structure — strided node walk, known-good).
// R20: per-lane fp16 packed accumulation (v_pk_fma_f16, 4 inst per 8 halfs
// vs 8 for fma_mix); cross-edge reduce stays f32 (error ~1 fp16 ulp since
// each lane's fp16 partial spans ~1.5 edges). Alpha packed pre-shfl.
// NOTE (R14): do NOT fuse the classifier MLP in here (occupancy collapse).
// NOTE (R16): do NOT switch to contiguous chunks + deep pipeline (56->76us).
// NOTE (R4): write-byte cuts don't speed this kernel; it is gather/issue-bound.
// ============================================================================
__global__ void k_ag(const int* __restrict__ rowptr, const int* __restrict__ csr_src,
                     const float* __restrict__ asrc, const float* __restrict__ adst,
                     const __half* __restrict__ xph, const float* __restrict__ b,
                     __half* __restrict__ hout, int N) {
    int tid = blockIdx.x * blockDim.x + threadIdx.x;
    int lane = threadIdx.x & 63;
    int wid = tid >> 6;
    int nw = (gridDim.x * blockDim.x) >> 6;
    const int l  = lane & 31;
    const int hh = lane >> 5;
    const int g4 = (lane >> 3) & 3;
    const int c8 = lane & 7;
    const int lofs = hh * 8 + c8;
    const uint4* xp4 = (const uint4*)xph;
    float4 bb0 = ((const float4*)b)[c8 * 2];
    float4 bb1 = ((const float4*)b)[c8 * 2 + 1];

    for (int n = wid; n < N; n += nw) {
        int rs = rowptr[n], re = rowptr[n + 1], cnt = re - rs;
        uint4 uself = xp4[(size_t)n * 16 + lofs];       // issue early; 2 lines/wave
        float a_dst = adst[n * 2 + hh];
        float eself = __expf(lrelu(asrc[n * 2 + hh] + a_dst));

        unsigned A0 = 0u, A1 = 0u, A2 = 0u, A3 = 0u;    // 4x half2 accumulators
        float den;

        if (cnt <= 32) {
            float ev = 0.f; int s_reg = n;
            if (l < cnt) {
                s_reg = csr_src[rs + l];
                ev = __expf(lrelu(asrc[s_reg * 2 + hh] + a_dst));
            }
            unsigned evp = pack2(ev, ev);               // packed alpha, pre-shfl
            if (g4 == 0) pk8(A0, A1, A2, A3, pack2(eself, eself), uself);

            const int base = (hh << 5) - rs;
            int e0 = rs;
            for (; e0 + 4 < re; e0 += 8) {
                int ea = e0 + g4, eb = e0 + 4 + g4;
                unsigned aa = __shfl(evp,   base + ea, 64);   // ea < re guaranteed
                int      sa = __shfl(s_reg, base + ea, 64);
                unsigned ab = __shfl(evp,   base + eb, 64);
                int      sb = __shfl(s_reg, base + eb, 64);
                if (eb >= re) { ab = 0u; sb = n; }
                uint4 u1 = xp4[(size_t)sa * 16 + lofs];
                uint4 u2 = xp4[(size_t)sb * 16 + lofs];
                pk8(A0, A1, A2, A3, aa, u1);
                pk8(A0, A1, A2, A3, ab, u2);
            }
            if (e0 < re) {                                  // wave-uniform 4-slot tail
                int ea = e0 + g4;
                unsigned aa = __shfl(evp,   base + ea, 64);
                int      sa = __shfl(s_reg, base + ea, 64);
                if (ea >= re) { aa = 0u; sa = n; }
                uint4 u1 = xp4[(size_t)sa * 16 + lofs];
                pk8(A0, A1, A2, A3, aa, u1);
            }
            // den reduce after gathers: shfls (LDS pipe) overlap vmcnt waits
            den = ev + (l == 0 ? eself : 0.f);
            #pragma unroll
            for (int off = 16; off > 0; off >>= 1) den += __shfl_xor(den, off, 64);
        } else {
            den = (l == 0) ? eself : 0.f;
            for (int e = rs + l; e < re; e += 32)
                den += __expf(lrelu(asrc[csr_src[e] * 2 + hh] + a_dst));
            #pragma unroll
            for (int off = 16; off > 0; off >>= 1) den += __shfl_xor(den, off, 64);
            if (g4 == 0) pk8(A0, A1, A2, A3, pack2(eself, eself), uself);
            for (int e0 = rs; e0 < re; e0 += 8) {
                int ea = e0 + g4, eb = e0 + 4 + g4;
                bool va = ea < re, vb = eb < re;
                int sa = va ? csr_src[ea] : n;
                int sb = vb ? csr_src[eb] : n;
                float fa = va ? __expf(lrelu(asrc[sa * 2 + hh] + a_dst)) : 0.f;
                float fb = vb ? __expf(lrelu(asrc[sb * 2 + hh] + a_dst)) : 0.f;
                unsigned aa = pack2(fa, fa);
                unsigned ab = pack2(fb, fb);
                uint4 u1 = xp4[(size_t)sa * 16 + lofs];
                uint4 u2 = xp4[(size_t)sb * 16 + lofs];
                pk8(A0, A1, A2, A3, aa, u1);
                pk8(A0, A1, A2, A3, ab, u2);
            }
        }

        float inv = 1.f / (den + 1e-16f);

        // convert packed fp16 partials -> f32 for the cross-lane reduce
        float2 f0 = h2f(A0), f1 = h2f(A1), f2 = h2f(A2), f3 = h2f(A3);
        float4 accA = make_float4(f0.x, f0.y, f1.x, f1.y);
        float4 accB = make_float4(f2.x, f2.y, f3.x, f3.y);

        // slot-group reduce (within head)
        #pragma unroll
        for (int off = 8; off <= 16; off <<= 1) {
            accA.x += __shfl_xor(accA.x, off, 64);
            accA.y += __shfl_xor(accA.y, off, 64);
            accA.z += __shfl_xor(accA.z, off, 64);
            accA.w += __shfl_xor(accA.w, off, 64);
            accB.x += __shfl_xor(accB.x, off, 64);
            accB.y += __shfl_xor(accB.y, off, 64);
            accB.z += __shfl_xor(accB.z, off, 64);
            accB.w += __shfl_xor(accB.w, off, 64);
        }
        // per-head normalization BEFORE head-mean exchange
        accA.x *= inv; accA.y *= inv; accA.z *= inv; accA.w *= inv;
        accB.x *= inv; accB.y *= inv; accB.z *= inv; accB.w *= inv;
        // head mean (xor 32 crosses the head boundary)
        accA.x += __shfl_xor(accA.x, 32, 64);
        accA.y += __shfl_xor(accA.y, 32, 64);
        accA.z += __shfl_xor(accA.z, 32, 64);
        accA.w += __shfl_xor(accA.w, 32, 64);
        accB.x += __shfl_xor(accB.x, 32, 64);
        accB.y += __shfl_xor(accB.y, 32, 64);
        accB.z += __shfl_xor(accB.z, 32, 64);
        accB.w += __shfl_xor(accB.w, 32, 64);

        if (lane < 8) {
            uint4 up;
            up.x = pack2(fmaxf(accA.x * 0.5f + bb0.x, 0.f),
                         fmaxf(accA.y * 0.5f + bb0.y, 0.f));
            up.y = pack2(fmaxf(accA.z * 0.5f + bb0.z, 0.f),
                         fmaxf(accA.w * 0.5f + bb0.w, 0.f));
            up.z = pack2(fmaxf(accB.x * 0.5f + bb1.x, 0.f),
                         fmaxf(accB.y * 0.5f + bb1.y, 0.f));
            up.w = pack2(fmaxf(accB.z * 0.5f + bb1.z, 0.f),
                         fmaxf(accB.w * 0.5f + bb1.w, 0.f));
            ((uint4*)hout)[(size_t)n * 8 + c8] = up;
        }
    }
}

// ============================================================================
// Final MLP, block-tile GEMM: 64 nodes/block, 256 threads, 4x4 micro-tile.
// h2 input is fp16. Kept SEPARATE from k_ag (see R14 note).
// ============================================================================
__global__ __launch_bounds__(256)
void k_final(const __half* __restrict__ h2, const float* __restrict__ cpre,
             const int* __restrict__ batch, const float* __restrict__ Wm1,
             const float* __restrict__ Wm2, const float* __restrict__ bm2,
             float* __restrict__ out, int N) {
    __shared__ float zs[64 * 65];
    __shared__ float ws[64 * 64];
    __shared__ float4 w2l[64];
    const int n0 = blockIdx.x * 64;
    const int t = threadIdx.x;

    for (int i = t; i < 1024; i += 256) ((float4*)ws)[i] = ((const float4*)Wm1)[i];
    if (t < 64) w2l[t] = ((const float4*)Wm2)[t];
    for (int i = t; i < 64 * 8; i += 256) {
        int n = i >> 3, k8 = i & 7;
        int gn = n0 + n;
        uint4 v = make_uint4(0u, 0u, 0u, 0u);
        if (gn < N) v = ((const uint4*)h2)[(size_t)gn * 8 + k8];
        float2 f0 = h2f(v.x), f1 = h2f(v.y), f2 = h2f(v.z), f3 = h2f(v.w);
        float* zr = zs + n * 65 + k8 * 8;
        zr[0] = f0.x; zr[1] = f0.y; zr[2] = f1.x; zr[3] = f1.y;
        zr[4] = f2.x; zr[5] = f2.y; zr[6] = f3.x; zr[7] = f3.y;
    }
    __syncthreads();

    const int tx = t & 15, ty = t >> 4;
    const int c0 = tx * 4;
    float acc[4][4];
    #pragma unroll
    for (int i = 0; i < 4; ++i)
        #pragma unroll
        for (int j = 0; j < 4; ++j) acc[i][j] = 0.f;

    for (int k = 0; k < 64; ++k) {
        float4 wv = *(const float4*)(ws + k * 64 + c0);
        #pragma unroll
        for (int i = 0; i < 4; ++i) {
            float zv = zs[(ty * 4 + i) * 65 + k];
            acc[i][0] += zv * wv.x; acc[i][1] += zv * wv.y;
            acc[i][2] += zv * wv.z; acc[i][3] += zv * wv.w;
        }
    }
    __syncthreads();

    float4 wa = w2l[c0], wb = w2l[c0 + 1], wc = w2l[c0 + 2], wd = w2l[c0 + 3];
    #pragma unroll
    for (int i = 0; i < 4; ++i) {
        int nl = ty * 4 + i, gn = n0 + nl;
        float4 o = make_float4(0.f, 0.f, 0.f, 0.f);
        if (gn < N) {
            int b = batch[gn];
            float4 cp = *(const float4*)(cpre + (size_t)b * 64 + c0);
            float m0 = fmaxf(acc[i][0] + cp.x, 0.f);
            float m1 = fmaxf(acc[i][1] + cp.y, 0.f);
            float m2 = fmaxf(acc[i][2] + cp.z, 0.f);
            float m3 = fmaxf(acc[i][3] + cp.w, 0.f);
            o.x = m0 * wa.x + m1 * wb.x + m2 * wc.x + m3 * wd.x;
            o.y = m0 * wa.y + m1 * wb.y + m2 * wc.y + m3 * wd.y;
            o.z = m0 * wa.z + m1 * wb.z + m2 * wc.z + m3 * wd.z;
            o.w = m0 * wa.w + m1 * wb.w + m2 * wc.w + m3 * wd.w;
        }
        *(float4*)(zs + tx * 260 + nl * 4) = o;
    }
    __syncthreads();
    {
        int nl = t >> 2, j = t & 3, gn = n0 + nl;
        float s = 0.f;
        #pragma unroll
        for (int tx2 = 0; tx2 < 16; ++tx2) s += zs[tx2 * 260 + nl * 4 + j];
        if (gn < N) out[(size_t)gn * 4 + j] = s + bm2[j];
    }
}

extern "C" void kernel_launch(void* const* d_in, const int* in_sizes, int n_in,
                              void* d_out, int out_size, void* d_ws, size_t ws_size,
                              hipStream_t stream) {
    const float* x       = (const float*)d_in[0];
    const int*   ei      = (const int*)  d_in[1];
    const int*   batch   = (const int*)  d_in[2];
    const float* climber = (const float*)d_in[3];
    const float* W1  = (const float*)d_in[4];
    const float* as1 = (const float*)d_in[5];
    const float* ad1 = (const float*)d_in[6];
    const float* b1  = (const float*)d_in[7];
    const float* W2  = (const float*)d_in[8];
    const float* as2 = (const float*)d_in[9];
    const float* ad2 = (const float*)d_in[10];
    const float* b2  = (const float*)d_in[11];
    const float* Wc  = (const float*)d_in[12];
    const float* bc  = (const float*)d_in[13];
    const float* Wm1 = (const float*)d_in[14];
    const float* bm1 = (const float*)d_in[15];
    const float* Wm2 = (const float*)d_in[16];
    const float* bm2 = (const float*)d_in[17];

    const int N  = in_sizes[0] / 6;
    const int E  = in_sizes[1] / 2;
    const int G  = in_sizes[3] / 4;

    const int* srcI = ei;
    const int* dstI = ei + E;

    // ---------------- workspace carve ----------------
    char* base = (char*)d_ws;
    size_t off = 0;
    auto carve = [&](size_t bytes) { void* p = base + off; off += (bytes + 255) & ~size_t(255); return p; };
    __half* xph   = (__half*)carve((size_t)N * 128 * 2);
    __half* hbuf  = (__half*)carve((size_t)N * 64 * 2);
    float* asrc   = (float*)carve((size_t)N * 2 * 4);
    float* adst   = (float*)carve((size_t)N * 2 * 4);
    float* cpre   = (float*)carve((size_t)G * 64 * 4);
    int*   deg    = (int*)  carve((size_t)N * 4);
    int*   rowptr = (int*)  carve((size_t)(N + 1) * 4);
    int*   rank   = (int*)  carve((size_t)E * 4);
    int*   partial= (int*)  carve(4096 * 4);
    int*   csr_src= (int*)  carve((size_t)E * 4);

    const int tpb = 256;
    const int nScanBlk = (N + 1023) / 1024;
    const int nEdgeBlk4 = (E + 1023) / 1024;     // 4 edges/thread
    const int nClimber = (G + 3) / 4;
    const int PG = 2048;
    const int nTile = (N + 63) / 64;

    // ---------------- CSR build + layer-1 projection + climber ----------
    hipMemsetAsync(deg, 0, (size_t)N * 4, stream);
    k_hist<<<nEdgeBlk4, tpb, 0, stream>>>(dstI, deg, rank, E);
    k_scan_partial<<<nScanBlk, tpb, 0, stream>>>(deg, partial, N);
    k_scan_final<<<nScanBlk, tpb, 0, stream>>>(deg, partial, rowptr, N, E, nScanBlk);
    k_fused3<<<nEdgeBlk4 + nTile + nClimber, tpb, 0, stream>>>(
        srcI, dstI, rowptr, rank, csr_src, E,
        x, W1, as1, ad1, xph, asrc, adst, N,
        climber, Wc, bc, Wm1, bm1, cpre, G, nEdgeBlk4, nTile);

    // ---------------- layer 1 aggregate ----------------
    k_ag<<<PG, tpb, 0, stream>>>(rowptr, csr_src, asrc, adst, xph, b1, hbuf, N);

    // ---------------- layer 2 ----------------
    k_xp_gemm64h<<<nTile, tpb, 0, stream>>>(hbuf, W2, as2, ad2, xph, asrc, adst, N);
    k_ag<<<PG, tpb, 0, stream>>>(rowptr, csr_src, asrc, adst, xph, b2, hbuf, N);

    // ---------------- classifier ----------------
    k_final<<<nTile, tpb, 0, stream>>>(hbuf, cpre, batch, Wm1, Wm2, bm2, (float*)d_out, N);
}

// Round 8
// 280.987 us; speedup vs baseline: 1.1284x; 1.1284x over previous
//
#include <hip/hip_runtime.h>
#include <hip/hip_fp16.h>

#define SLOPE 0.2f
#define BKW  512            // bucket width in nodes
#define BKSH 9
#define MAXB 256            // max buckets (N <= 131072); N=100k -> 196

__device__ __forceinline__ float lrelu(float v) { return v >= 0.f ? v : SLOPE * v; }

__device__ __forceinline__ unsigned pack2(float a, float b) {
    __half2 h = __floats2half2_rn(a, b);
    return *reinterpret_cast<unsigned*>(&h);
}
__device__ __forceinline__ float2 h2f(unsigned u) {
    __half2 h = *reinterpret_cast<__half2*>(&u);
    return __half22float2(h);
}

// 8 half elements scaled by packed-half2, accumulated via v_pk_fma_f16 (R20).
__device__ __forceinline__ void pk8(unsigned& A0, unsigned& A1, unsigned& A2, unsigned& A3,
                                    unsigned ap, uint4 u) {
    __half2 a = *reinterpret_cast<__half2*>(&ap);
    __half2* up = reinterpret_cast<__half2*>(&u);
    *reinterpret_cast<__half2*>(&A0) = __hfma2(up[0], a, *reinterpret_cast<__half2*>(&A0));
    *reinterpret_cast<__half2*>(&A1) = __hfma2(up[1], a, *reinterpret_cast<__half2*>(&A1));
    *reinterpret_cast<__half2*>(&A2) = __hfma2(up[2], a, *reinterpret_cast<__half2*>(&A2));
    *reinterpret_cast<__half2*>(&A3) = __hfma2(up[3], a, *reinterpret_cast<__half2*>(&A3));
}

// ============================================================================
// xp = h @ W (64 -> 128) + attention dots, block-tile GEMM. h fp16 input.
// ============================================================================
__global__ __launch_bounds__(256)
void k_xp_gemm64h(const __half* __restrict__ x, const float* __restrict__ W,
                  const float* __restrict__ as_, const float* __restrict__ ad_,
                  __half* __restrict__ xph, float* __restrict__ asrc,
                  float* __restrict__ adst, int N) {
    constexpr int K = 64;
    constexpr int ZS = K + 1;
    __shared__ float zs[64 * ZS];
    __shared__ float ws[K * 128];
    const int n0 = blockIdx.x * 64;
    const int t = threadIdx.x;

    for (int i = t; i < K * 32; i += 256) ((float4*)ws)[i] = ((const float4*)W)[i];
    for (int i = t; i < 64 * 8; i += 256) {
        int n = i >> 3, k8 = i & 7;
        int gn = n0 + n;
        uint4 v = make_uint4(0u, 0u, 0u, 0u);
        if (gn < N) v = ((const uint4*)x)[(size_t)gn * 8 + k8];
        float2 f0 = h2f(v.x), f1 = h2f(v.y), f2 = h2f(v.z), f3 = h2f(v.w);
        float* zr = zs + n * ZS + k8 * 8;
        zr[0] = f0.x; zr[1] = f0.y; zr[2] = f1.x; zr[3] = f1.y;
        zr[4] = f2.x; zr[5] = f2.y; zr[6] = f3.x; zr[7] = f3.y;
    }
    __syncthreads();

    const int tx = t & 15, ty = t >> 4;
    const int c0a = tx * 4;
    const int c0b = 64 + tx * 4;

    float4 asA = *(const float4*)(as_ + c0a);
    float4 asB = *(const float4*)(as_ + c0b);
    float4 adA = *(const float4*)(ad_ + c0a);
    float4 adB = *(const float4*)(ad_ + c0b);

    float acc[4][8];
    #pragma unroll
    for (int i = 0; i < 4; ++i)
        #pragma unroll
        for (int j = 0; j < 8; ++j) acc[i][j] = 0.f;

    for (int k = 0; k < K; ++k) {
        float4 w0 = *(const float4*)(ws + k * 128 + c0a);
        float4 w1 = *(const float4*)(ws + k * 128 + c0b);
        #pragma unroll
        for (int i = 0; i < 4; ++i) {
            float zv = zs[(ty * 4 + i) * ZS + k];
            acc[i][0] += zv * w0.x; acc[i][1] += zv * w0.y;
            acc[i][2] += zv * w0.z; acc[i][3] += zv * w0.w;
            acc[i][4] += zv * w1.x; acc[i][5] += zv * w1.y;
            acc[i][6] += zv * w1.z; acc[i][7] += zv * w1.w;
        }
    }

    #pragma unroll
    for (int i = 0; i < 4; ++i) {
        int nl = ty * 4 + i, gn = n0 + nl;
        if (gn < N) {
            uint2 ua, ub;
            ua.x = pack2(acc[i][0], acc[i][1]);
            ua.y = pack2(acc[i][2], acc[i][3]);
            ub.x = pack2(acc[i][4], acc[i][5]);
            ub.y = pack2(acc[i][6], acc[i][7]);
            *(uint2*)(xph + (size_t)gn * 128 + c0a) = ua;
            *(uint2*)(xph + (size_t)gn * 128 + c0b) = ub;
        }
        float ps0 = acc[i][0]*asA.x + acc[i][1]*asA.y + acc[i][2]*asA.z + acc[i][3]*asA.w;
        float ps1 = acc[i][4]*asB.x + acc[i][5]*asB.y + acc[i][6]*asB.z + acc[i][7]*asB.w;
        float pd0 = acc[i][0]*adA.x + acc[i][1]*adA.y + acc[i][2]*adA.z + acc[i][3]*adA.w;
        float pd1 = acc[i][4]*adB.x + acc[i][5]*adB.y + acc[i][6]*adB.z + acc[i][7]*adB.w;
        #pragma unroll
        for (int off = 1; off <= 8; off <<= 1) {
            ps0 += __shfl_xor(ps0, off, 64);
            ps1 += __shfl_xor(ps1, off, 64);
            pd0 += __shfl_xor(pd0, off, 64);
            pd1 += __shfl_xor(pd1, off, 64);
        }
        if (tx == 0 && gn < N) {
            asrc[gn * 2]     = ps0;
            asrc[gn * 2 + 1] = ps1;
            adst[gn * 2]     = pd0;
            adst[gn * 2 + 1] = pd1;
        }
    }
}

// ============================================================================
// R21 CSR BUILD via bucket radix partition — replaces 1M global returning
// atomics (hist) + random 4B scatter (16x write amplification, R5 evidence:
// WRITE_SIZE 69MB on a 4MB array).
//   k_bcount: LDS-aggregated bucket histogram (196 atomics/block, not 4096)
//   k_bscan:  one-block exclusive scan of bucket counts
//   k_part:   LDS-staged partition; writes (src,dst) in contiguous runs
//   k_build:  per-bucket LDS hist+scan+place; coalesced rowptr/csr writes
// ============================================================================
__global__ __launch_bounds__(256)
void k_bcount(const int* __restrict__ dst, int* __restrict__ bkt_cnt, int E, int nb) {
    __shared__ int cnt[MAXB];
    int t = threadIdx.x;
    for (int i = t; i < MAXB; i += 256) cnt[i] = 0;
    __syncthreads();
    int be = blockIdx.x * 4096;
    int n = min(4096, E - be);
    const int4* d4 = (const int4*)(dst + be);
    #pragma unroll
    for (int i = 0; i < 4; ++i) {
        int j = t + 256 * i, r = j * 4;
        if (r < n) {
            int4 d = d4[j];
            if (r + 0 < n) atomicAdd(&cnt[d.x >> BKSH], 1);
            if (r + 1 < n) atomicAdd(&cnt[d.y >> BKSH], 1);
            if (r + 2 < n) atomicAdd(&cnt[d.z >> BKSH], 1);
            if (r + 3 < n) atomicAdd(&cnt[d.w >> BKSH], 1);
        }
    }
    __syncthreads();
    for (int b = t; b < nb; b += 256) if (cnt[b]) atomicAdd(&bkt_cnt[b], cnt[b]);
}

__global__ __launch_bounds__(256)
void k_bscan(const int* __restrict__ bkt_cnt, int* __restrict__ bkt_base,
             int* __restrict__ bkt_cur, int nb, int E) {
    __shared__ int sh[256];
    int t = threadIdx.x;
    int v = (t < nb) ? bkt_cnt[t] : 0;
    int orig = v;
    sh[t] = v; __syncthreads();
    for (int off = 1; off < 256; off <<= 1) {
        int u = (t >= off) ? sh[t - off] : 0;
        __syncthreads(); sh[t] += u; __syncthreads();
    }
    int base = sh[t] - orig;
    if (t < nb) { bkt_base[t] = base; bkt_cur[t] = base; }
    if (t == 0) bkt_base[nb] = E;
}

__global__ __launch_bounds__(256)
void k_part(const int* __restrict__ src, const int* __restrict__ dst,
            int* __restrict__ bkt_cur, uint2* __restrict__ ebuf, int E) {
    __shared__ int cnt[MAXB];
    __shared__ int shift[MAXB];
    __shared__ int cur[MAXB];
    __shared__ int sh[256];
    __shared__ uint2 data[4096];
    __shared__ unsigned char bof[4096];
    int t = threadIdx.x;
    cnt[t] = 0;
    __syncthreads();
    int be = blockIdx.x * 4096;
    int n = min(4096, E - be);
    const int4* d4 = (const int4*)(dst + be);
    const int4* s4 = (const int4*)(src + be);
    // sweep 1: bucket histogram of this chunk
    #pragma unroll
    for (int i = 0; i < 4; ++i) {
        int j = t + 256 * i, r = j * 4;
        if (r < n) {
            int4 d = d4[j];
            if (r + 0 < n) atomicAdd(&cnt[d.x >> BKSH], 1);
            if (r + 1 < n) atomicAdd(&cnt[d.y >> BKSH], 1);
            if (r + 2 < n) atomicAdd(&cnt[d.z >> BKSH], 1);
            if (r + 3 < n) atomicAdd(&cnt[d.w >> BKSH], 1);
        }
    }
    __syncthreads();
    // exclusive scan of cnt (256 entries, 256 threads)
    int v = cnt[t], orig = v;
    sh[t] = v; __syncthreads();
    for (int off = 1; off < 256; off <<= 1) {
        int u = (t >= off) ? sh[t - off] : 0;
        __syncthreads(); sh[t] += u; __syncthreads();
    }
    int lb = sh[t] - orig;
    cur[t] = lb;
    if (orig > 0) {
        int g = atomicAdd(&bkt_cur[t], orig);   // reserve global range
        shift[t] = g - lb;
    }
    __syncthreads();
    // sweep 2: stage edges grouped by bucket in LDS
    #pragma unroll
    for (int i = 0; i < 4; ++i) {
        int j = t + 256 * i, r = j * 4;
        if (r < n) {
            int4 d = d4[j]; int4 s = s4[j];
            if (r + 0 < n) { int b = d.x >> BKSH; int p = atomicAdd(&cur[b], 1); data[p] = make_uint2((unsigned)s.x, (unsigned)d.x); bof[p] = (unsigned char)b; }
            if (r + 1 < n) { int b = d.y >> BKSH; int p = atomicAdd(&cur[b], 1); data[p] = make_uint2((unsigned)s.y, (unsigned)d.y); bof[p] = (unsigned char)b; }
            if (r + 2 < n) { int b = d.z >> BKSH; int p = atomicAdd(&cur[b], 1); data[p] = make_uint2((unsigned)s.z, (unsigned)d.z); bof[p] = (unsigned char)b; }
            if (r + 3 < n) { int b = d.w >> BKSH; int p = atomicAdd(&cur[b], 1); data[p] = make_uint2((unsigned)s.w, (unsigned)d.w); bof[p] = (unsigned char)b; }
        }
    }
    __syncthreads();
    // sweep 3: write out — consecutive staged entries of one bucket land at
    // consecutive global addresses (coalesced runs)
    for (int j = t; j < n; j += 256) {
        int b = bof[j];
        ebuf[shift[b] + j] = data[j];
    }
}

// ============================================================================
// k_build (+ gemm6 + climber fused, branched on blockIdx):
//   [0, nb)            -> per-bucket CSR build (LDS-only atomics)
//   [nb, nb+nTile)     -> xp_gemm K=6 (layer-1 projection)
//   [.., +nClimber)    -> climber embed + cpre
// ============================================================================
__global__ __launch_bounds__(256)
void k_build(const uint2* __restrict__ ebuf, const int* __restrict__ bkt_base,
             int* __restrict__ rowptr, int* __restrict__ csr_src, int N, int E, int nb,
             const float* __restrict__ x, const float* __restrict__ W1,
             const float* __restrict__ as1, const float* __restrict__ ad1,
             __half* __restrict__ xph, float* __restrict__ asrc,
             float* __restrict__ adst,
             const float* __restrict__ climber, const float* __restrict__ Wc,
             const float* __restrict__ bc, const float* __restrict__ Wm1,
             const float* __restrict__ bm1, float* __restrict__ cpre, int G,
             int nTile) {
    __shared__ char smem[17408];        // 4352 floats; build uses 7KB as ints
    __shared__ int sh[256];
    int bid = blockIdx.x;
    const int t = threadIdx.x;

    if (bid < nb) {
        int* deg = (int*)smem;          // 512
        int* pre = deg + 512;           // 512
        int* cur = pre + 512;           // 512
        int n0 = bid << BKSH;
        int nn = min(BKW, N - n0);
        int eb = bkt_base[bid], ee = bkt_base[bid + 1];
        for (int i = t; i < BKW; i += 256) deg[i] = 0;
        __syncthreads();
        for (int j = eb + t; j < ee; j += 256)
            atomicAdd(&deg[(int)ebuf[j].y - n0], 1);
        __syncthreads();
        // exclusive scan of deg[512]: thread owns elems 2t, 2t+1
        int a = deg[2 * t], b2 = deg[2 * t + 1];
        int s = a + b2, orig = s;
        sh[t] = s; __syncthreads();
        for (int off = 1; off < 256; off <<= 1) {
            int u = (t >= off) ? sh[t - off] : 0;
            __syncthreads(); sh[t] += u; __syncthreads();
        }
        int base = sh[t] - orig;
        pre[2 * t] = base; pre[2 * t + 1] = base + a;
        cur[2 * t] = base; cur[2 * t + 1] = base + a;
        __syncthreads();
        for (int i = t; i < nn; i += 256) rowptr[n0 + i] = eb + pre[i];
        // place: csr writes land in a hot ~20KB region (L2-absorbed)
        for (int j = eb + t; j < ee; j += 256) {
            uint2 e = ebuf[j];
            int lp = atomicAdd(&cur[(int)e.y - n0], 1);
            csr_src[eb + lp] = (int)e.x;
        }
        if (bid == 0 && t == 0) rowptr[N] = E;
        return;
    }
    bid -= nb;
    if (bid < nTile) {
        // ---- xp_gemm K=6 ----
        constexpr int K = 6, ZS = 7;
        float* smf = (float*)smem;
        float* zs = smf;                // 64*7  = 448
        float* ws = smf + 448;          // 6*128 = 768
        const int n0 = bid * 64;

        for (int i = t; i < K * 32; i += 256) ((float4*)ws)[i] = ((const float4*)W1)[i];
        for (int i = t; i < 64 * K; i += 256) {
            int n = i / K, k = i - n * K;
            int gn = n0 + n;
            zs[n * ZS + k] = (gn < N) ? x[(size_t)gn * K + k] : 0.f;
        }
        __syncthreads();

        const int tx = t & 15, ty = t >> 4;
        const int c0a = tx * 4;
        const int c0b = 64 + tx * 4;

        float4 asA = *(const float4*)(as1 + c0a);
        float4 asB = *(const float4*)(as1 + c0b);
        float4 adA = *(const float4*)(ad1 + c0a);
        float4 adB = *(const float4*)(ad1 + c0b);

        float acc[4][8];
        #pragma unroll
        for (int i = 0; i < 4; ++i)
            #pragma unroll
            for (int j = 0; j < 8; ++j) acc[i][j] = 0.f;

        for (int k = 0; k < K; ++k) {
            float4 w0 = *(const float4*)(ws + k * 128 + c0a);
            float4 w1 = *(const float4*)(ws + k * 128 + c0b);
            #pragma unroll
            for (int i = 0; i < 4; ++i) {
                float zv = zs[(ty * 4 + i) * ZS + k];
                acc[i][0] += zv * w0.x; acc[i][1] += zv * w0.y;
                acc[i][2] += zv * w0.z; acc[i][3] += zv * w0.w;
                acc[i][4] += zv * w1.x; acc[i][5] += zv * w1.y;
                acc[i][6] += zv * w1.z; acc[i][7] += zv * w1.w;
            }
        }

        #pragma unroll
        for (int i = 0; i < 4; ++i) {
            int nl = ty * 4 + i, gn = n0 + nl;
            if (gn < N) {
                uint2 ua, ub;
                ua.x = pack2(acc[i][0], acc[i][1]);
                ua.y = pack2(acc[i][2], acc[i][3]);
                ub.x = pack2(acc[i][4], acc[i][5]);
                ub.y = pack2(acc[i][6], acc[i][7]);
                *(uint2*)(xph + (size_t)gn * 128 + c0a) = ua;
                *(uint2*)(xph + (size_t)gn * 128 + c0b) = ub;
            }
            float ps0 = acc[i][0]*asA.x + acc[i][1]*asA.y + acc[i][2]*asA.z + acc[i][3]*asA.w;
            float ps1 = acc[i][4]*asB.x + acc[i][5]*asB.y + acc[i][6]*asB.z + acc[i][7]*asB.w;
            float pd0 = acc[i][0]*adA.x + acc[i][1]*adA.y + acc[i][2]*adA.z + acc[i][3]*adA.w;
            float pd1 = acc[i][4]*adB.x + acc[i][5]*adB.y + acc[i][6]*adB.z + acc[i][7]*adB.w;
            #pragma unroll
            for (int off = 1; off <= 8; off <<= 1) {
                ps0 += __shfl_xor(ps0, off, 64);
                ps1 += __shfl_xor(ps1, off, 64);
                pd0 += __shfl_xor(pd0, off, 64);
                pd1 += __shfl_xor(pd1, off, 64);
            }
            if (tx == 0 && gn < N) {
                asrc[gn * 2]     = ps0;
                asrc[gn * 2 + 1] = ps1;
                adst[gn * 2]     = pd0;
                adst[gn * 2 + 1] = pd1;
            }
        }
        return;
    }
    bid -= nTile;
    {
        // ---- climber embed + cpre ----
        float* smf = (float*)smem;
        float* ce   = smf;              // 4*64
        float* wm1b = smf + 256;        // 64*64
        for (int i = t; i < 1024; i += 256) ((float4*)wm1b)[i] = ((const float4*)Wm1)[1024 + i];
        int gl = t >> 6, c = t & 63;
        int g = bid * 4 + gl;
        float acc = bc[c];
        if (g < G)
            for (int k = 0; k < 4; ++k) acc += climber[g * 4 + k] * Wc[k * 64 + c];
        ce[gl * 64 + c] = fmaxf(acc, 0.f);
        __syncthreads();
        float o = bm1[c];
        for (int k = 0; k < 64; ++k) o += ce[gl * 64 + k] * wm1b[k * 64 + c];
        if (g < G) cpre[(size_t)g * 64 + c] = o;
    }
}

// ============================================================================
// FUSED softmax + gather (R1 structure, strided node walk; pk8 R20).
// NOTE (R14): do NOT fuse the classifier MLP in here (occupancy collapse).
// NOTE (R16): do NOT switch to contiguous chunks + deep pipeline (56->76us).
// NOTE (R4): write-byte cuts don't speed this kernel; it is gather/issue-bound.
// ============================================================================
__global__ void k_ag(const int* __restrict__ rowptr, const int* __restrict__ csr_src,
                     const float* __restrict__ asrc, const float* __restrict__ adst,
                     const __half* __restrict__ xph, const float* __restrict__ b,
                     __half* __restrict__ hout, int N) {
    int tid = blockIdx.x * blockDim.x + threadIdx.x;
    int lane = threadIdx.x & 63;
    int wid = tid >> 6;
    int nw = (gridDim.x * blockDim.x) >> 6;
    const int l  = lane & 31;
    const int hh = lane >> 5;
    const int g4 = (lane >> 3) & 3;
    const int c8 = lane & 7;
    const int lofs = hh * 8 + c8;
    const uint4* xp4 = (const uint4*)xph;
    float4 bb0 = ((const float4*)b)[c8 * 2];
    float4 bb1 = ((const float4*)b)[c8 * 2 + 1];

    for (int n = wid; n < N; n += nw) {
        int rs = rowptr[n], re = rowptr[n + 1], cnt = re - rs;
        uint4 uself = xp4[(size_t)n * 16 + lofs];
        float a_dst = adst[n * 2 + hh];
        float eself = __expf(lrelu(asrc[n * 2 + hh] + a_dst));

        unsigned A0 = 0u, A1 = 0u, A2 = 0u, A3 = 0u;
        float den;

        if (cnt <= 32) {
            float ev = 0.f; int s_reg = n;
            if (l < cnt) {
                s_reg = csr_src[rs + l];
                ev = __expf(lrelu(asrc[s_reg * 2 + hh] + a_dst));
            }
            unsigned evp = pack2(ev, ev);
            if (g4 == 0) pk8(A0, A1, A2, A3, pack2(eself, eself), uself);

            const int base = (hh << 5) - rs;
            int e0 = rs;
            for (; e0 + 4 < re; e0 += 8) {
                int ea = e0 + g4, eb = e0 + 4 + g4;
                unsigned aa = __shfl(evp,   base + ea, 64);
                int      sa = __shfl(s_reg, base + ea, 64);
                unsigned ab = __shfl(evp,   base + eb, 64);
                int      sb = __shfl(s_reg, base + eb, 64);
                if (eb >= re) { ab = 0u; sb = n; }
                uint4 u1 = xp4[(size_t)sa * 16 + lofs];
                uint4 u2 = xp4[(size_t)sb * 16 + lofs];
                pk8(A0, A1, A2, A3, aa, u1);
                pk8(A0, A1, A2, A3, ab, u2);
            }
            if (e0 < re) {
                int ea = e0 + g4;
                unsigned aa = __shfl(evp,   base + ea, 64);
                int      sa = __shfl(s_reg, base + ea, 64);
                if (ea >= re) { aa = 0u; sa = n; }
                uint4 u1 = xp4[(size_t)sa * 16 + lofs];
                pk8(A0, A1, A2, A3, aa, u1);
            }
            den = ev + (l == 0 ? eself : 0.f);
            #pragma unroll
            for (int off = 16; off > 0; off >>= 1) den += __shfl_xor(den, off, 64);
        } else {
            den = (l == 0) ? eself : 0.f;
            for (int e = rs + l; e < re; e += 32)
                den += __expf(lrelu(asrc[csr_src[e] * 2 + hh] + a_dst));
            #pragma unroll
            for (int off = 16; off > 0; off >>= 1) den += __shfl_xor(den, off, 64);
            if (g4 == 0) pk8(A0, A1, A2, A3, pack2(eself, eself), uself);
            for (int e0 = rs; e0 < re; e0 += 8) {
                int ea = e0 + g4, eb = e0 + 4 + g4;
                bool va = ea < re, vb = eb < re;
                int sa = va ? csr_src[ea] : n;
                int sb = vb ? csr_src[eb] : n;
                float fa = va ? __expf(lrelu(asrc[sa * 2 + hh] + a_dst)) : 0.f;
                float fb = vb ? __expf(lrelu(asrc[sb * 2 + hh] + a_dst)) : 0.f;
                unsigned aa = pack2(fa, fa);
                unsigned ab = pack2(fb, fb);
                uint4 u1 = xp4[(size_t)sa * 16 + lofs];
                uint4 u2 = xp4[(size_t)sb * 16 + lofs];
                pk8(A0, A1, A2, A3, aa, u1);
                pk8(A0, A1, A2, A3, ab, u2);
            }
        }

        float inv = 1.f / (den + 1e-16f);

        float2 f0 = h2f(A0), f1 = h2f(A1), f2 = h2f(A2), f3 = h2f(A3);
        float4 accA = make_float4(f0.x, f0.y, f1.x, f1.y);
        float4 accB = make_float4(f2.x, f2.y, f3.x, f3.y);

        #pragma unroll
        for (int off = 8; off <= 16; off <<= 1) {
            accA.x += __shfl_xor(accA.x, off, 64);
            accA.y += __shfl_xor(accA.y, off, 64);
            accA.z += __shfl_xor(accA.z, off, 64);
            accA.w += __shfl_xor(accA.w, off, 64);
            accB.x += __shfl_xor(accB.x, off, 64);
            accB.y += __shfl_xor(accB.y, off, 64);
            accB.z += __shfl_xor(accB.z, off, 64);
            accB.w += __shfl_xor(accB.w, off, 64);
        }
        accA.x *= inv; accA.y *= inv; accA.z *= inv; accA.w *= inv;
        accB.x *= inv; accB.y *= inv; accB.z *= inv; accB.w *= inv;
        accA.x += __shfl_xor(accA.x, 32, 64);
        accA.y += __shfl_xor(accA.y, 32, 64);
        accA.z += __shfl_xor(accA.z, 32, 64);
        accA.w += __shfl_xor(accA.w, 32, 64);
        accB.x += __shfl_xor(accB.x, 32, 64);
        accB.y += __shfl_xor(accB.y, 32, 64);
        accB.z += __shfl_xor(accB.z, 32, 64);
        accB.w += __shfl_xor(accB.w, 32, 64);

        if (lane < 8) {
            uint4 up;
            up.x = pack2(fmaxf(accA.x * 0.5f + bb0.x, 0.f),
                         fmaxf(accA.y * 0.5f + bb0.y, 0.f));
            up.y = pack2(fmaxf(accA.z * 0.5f + bb0.z, 0.f),
                         fmaxf(accA.w * 0.5f + bb0.w, 0.f));
            up.z = pack2(fmaxf(accB.x * 0.5f + bb1.x, 0.f),
                         fmaxf(accB.y * 0.5f + bb1.y, 0.f));
            up.w = pack2(fmaxf(accB.z * 0.5f + bb1.z, 0.f),
                         fmaxf(accB.w * 0.5f + bb1.w, 0.f));
            ((uint4*)hout)[(size_t)n * 8 + c8] = up;
        }
    }
}

// ============================================================================
// Final MLP, block-tile GEMM. h2 fp16. Kept SEPARATE from k_ag (R14).
// ============================================================================
__global__ __launch_bounds__(256)
void k_final(const __half* __restrict__ h2, const float* __restrict__ cpre,
             const int* __restrict__ batch, const float* __restrict__ Wm1,
             const float* __restrict__ Wm2, const float* __restrict__ bm2,
             float* __restrict__ out, int N) {
    __shared__ float zs[64 * 65];
    __shared__ float ws[64 * 64];
    __shared__ float4 w2l[64];
    const int n0 = blockIdx.x * 64;
    const int t = threadIdx.x;

    for (int i = t; i < 1024; i += 256) ((float4*)ws)[i] = ((const float4*)Wm1)[i];
    if (t < 64) w2l[t] = ((const float4*)Wm2)[t];
    for (int i = t; i < 64 * 8; i += 256) {
        int n = i >> 3, k8 = i & 7;
        int gn = n0 + n;
        uint4 v = make_uint4(0u, 0u, 0u, 0u);
        if (gn < N) v = ((const uint4*)h2)[(size_t)gn * 8 + k8];
        float2 f0 = h2f(v.x), f1 = h2f(v.y), f2 = h2f(v.z), f3 = h2f(v.w);
        float* zr = zs + n * 65 + k8 * 8;
        zr[0] = f0.x; zr[1] = f0.y; zr[2] = f1.x; zr[3] = f1.y;
        zr[4] = f2.x; zr[5] = f2.y; zr[6] = f3.x; zr[7] = f3.y;
    }
    __syncthreads();

    const int tx = t & 15, ty = t >> 4;
    const int c0 = tx * 4;
    float acc[4][4];
    #pragma unroll
    for (int i = 0; i < 4; ++i)
        #pragma unroll
        for (int j = 0; j < 4; ++j) acc[i][j] = 0.f;

    for (int k = 0; k < 64; ++k) {
        float4 wv = *(const float4*)(ws + k * 64 + c0);
        #pragma unroll
        for (int i = 0; i < 4; ++i) {
            float zv = zs[(ty * 4 + i) * 65 + k];
            acc[i][0] += zv * wv.x; acc[i][1] += zv * wv.y;
            acc[i][2] += zv * wv.z; acc[i][3] += zv * wv.w;
        }
    }
    __syncthreads();

    float4 wa = w2l[c0], wb = w2l[c0 + 1], wc = w2l[c0 + 2], wd = w2l[c0 + 3];
    #pragma unroll
    for (int i = 0; i < 4; ++i) {
        int nl = ty * 4 + i, gn = n0 + nl;
        float4 o = make_float4(0.f, 0.f, 0.f, 0.f);
        if (gn < N) {
            int b = batch[gn];
            float4 cp = *(const float4*)(cpre + (size_t)b * 64 + c0);
            float m0 = fmaxf(acc[i][0] + cp.x, 0.f);
            float m1 = fmaxf(acc[i][1] + cp.y, 0.f);
            float m2 = fmaxf(acc[i][2] + cp.z, 0.f);
            float m3 = fmaxf(acc[i][3] + cp.w, 0.f);
            o.x = m0 * wa.x + m1 * wb.x + m2 * wc.x + m3 * wd.x;
            o.y = m0 * wa.y + m1 * wb.y + m2 * wc.y + m3 * wd.y;
            o.z = m0 * wa.z + m1 * wb.z + m2 * wc.z + m3 * wd.z;
            o.w = m0 * wa.w + m1 * wb.w + m2 * wc.w + m3 * wd.w;
        }
        *(float4*)(zs + tx * 260 + nl * 4) = o;
    }
    __syncthreads();
    {
        int nl = t >> 2, j = t & 3, gn = n0 + nl;
        float s = 0.f;
        #pragma unroll
        for (int tx2 = 0; tx2 < 16; ++tx2) s += zs[tx2 * 260 + nl * 4 + j];
        if (gn < N) out[(size_t)gn * 4 + j] = s + bm2[j];
    }
}

extern "C" void kernel_launch(void* const* d_in, const int* in_sizes, int n_in,
                              void* d_out, int out_size, void* d_ws, size_t ws_size,
                              hipStream_t stream) {
    const float* x       = (const float*)d_in[0];
    const int*   ei      = (const int*)  d_in[1];
    const int*   batch   = (const int*)  d_in[2];
    const float* climber = (const float*)d_in[3];
    const float* W1  = (const float*)d_in[4];
    const float* as1 = (const float*)d_in[5];
    const float* ad1 = (const float*)d_in[6];
    const float* b1  = (const float*)d_in[7];
    const float* W2  = (const float*)d_in[8];
    const float* as2 = (const float*)d_in[9];
    const float* ad2 = (const float*)d_in[10];
    const float* b2  = (const float*)d_in[11];
    const float* Wc  = (const float*)d_in[12];
    const float* bc  = (const float*)d_in[13];
    const float* Wm1 = (const float*)d_in[14];
    const float* bm1 = (const float*)d_in[15];
    const float* Wm2 = (const float*)d_in[16];
    const float* bm2 = (const float*)d_in[17];

    const int N  = in_sizes[0] / 6;
    const int E  = in_sizes[1] / 2;
    const int G  = in_sizes[3] / 4;

    const int* srcI = ei;
    const int* dstI = ei + E;

    // ---------------- workspace carve ----------------
    char* base = (char*)d_ws;
    size_t off = 0;
    auto carve = [&](size_t bytes) { void* p = base + off; off += (bytes + 255) & ~size_t(255); return p; };
    __half* xph    = (__half*)carve((size_t)N * 128 * 2);
    __half* hbuf   = (__half*)carve((size_t)N * 64 * 2);
    float* asrc    = (float*)carve((size_t)N * 2 * 4);
    float* adst    = (float*)carve((size_t)N * 2 * 4);
    float* cpre    = (float*)carve((size_t)G * 64 * 4);
    int*   rowptr  = (int*)  carve((size_t)(N + 1) * 4);
    int*   csr_src = (int*)  carve((size_t)E * 4);
    uint2* ebuf    = (uint2*)carve((size_t)E * 8);
    int*   bkt_cnt = (int*)  carve((size_t)MAXB * 4);
    int*   bkt_base= (int*)  carve((size_t)(MAXB + 1) * 4);
    int*   bkt_cur = (int*)  carve((size_t)MAXB * 4);

    const int tpb = 256;
    const int nb = (N + BKW - 1) >> BKSH;        // buckets (<= MAXB for N<=131072)
    const int nChunk = (E + 4095) / 4096;
    const int nClimber = (G + 3) / 4;
    const int PG = 2048;
    const int nTile = (N + 63) / 64;

    // ---------------- CSR via bucket radix partition (R21) ----------------
    hipMemsetAsync(bkt_cnt, 0, (size_t)nb * 4, stream);
    k_bcount<<<nChunk, tpb, 0, stream>>>(dstI, bkt_cnt, E, nb);
    k_bscan<<<1, tpb, 0, stream>>>(bkt_cnt, bkt_base, bkt_cur, nb, E);
    k_part<<<nChunk, tpb, 0, stream>>>(srcI, dstI, bkt_cur, ebuf, E);
    k_build<<<nb + nTile + nClimber, tpb, 0, stream>>>(
        ebuf, bkt_base, rowptr, csr_src, N, E, nb,
        x, W1, as1, ad1, xph, asrc, adst,
        climber, Wc, bc, Wm1, bm1, cpre, G, nTile);

    // ---------------- layer 1 aggregate ----------------
    k_ag<<<PG, tpb, 0, stream>>>(rowptr, csr_src, asrc, adst, xph, b1, hbuf, N);

    // ---------------- layer 2 ----------------
    k_xp_gemm64h<<<nTile, tpb, 0, stream>>>(hbuf, W2, as2, ad2, xph, asrc, adst, N);
    k_ag<<<PG, tpb, 0, stream>>>(rowptr, csr_src, asrc, adst, xph, b2, hbuf, N);

    // ---------------- classifier ----------------
    k_final<<<nTile, tpb, 0, stream>>>(hbuf, cpre, batch, Wm1, Wm2, bm2, (float*)d_out, N);
}

// Round 9
// 275.220 us; speedup vs baseline: 1.1521x; 1.0210x over previous
//
#include <hip/hip_runtime.h>
#include <hip/hip_fp16.h>

#define SLOPE 0.2f
#define BKW  512            // bucket width in nodes
#define BKSH 9
#define MAXB 256            // max buckets (N <= 131072); N=100k -> 196

typedef _Float16 half8 __attribute__((ext_vector_type(8)));
typedef float f32x4 __attribute__((ext_vector_type(4)));

__device__ __forceinline__ float lrelu(float v) { return v >= 0.f ? v : SLOPE * v; }

__device__ __forceinline__ unsigned pack2(float a, float b) {
    __half2 h = __floats2half2_rn(a, b);
    return *reinterpret_cast<unsigned*>(&h);
}
__device__ __forceinline__ float2 h2f(unsigned u) {
    __half2 h = *reinterpret_cast<__half2*>(&u);
    return __half22float2(h);
}

// 8 half elements scaled by packed-half2, accumulated via v_pk_fma_f16 (R20).
__device__ __forceinline__ void pk8(unsigned& A0, unsigned& A1, unsigned& A2, unsigned& A3,
                                    unsigned ap, uint4 u) {
    __half2 a = *reinterpret_cast<__half2*>(&ap);
    __half2* up = reinterpret_cast<__half2*>(&u);
    *reinterpret_cast<__half2*>(&A0) = __hfma2(up[0], a, *reinterpret_cast<__half2*>(&A0));
    *reinterpret_cast<__half2*>(&A1) = __hfma2(up[1], a, *reinterpret_cast<__half2*>(&A1));
    *reinterpret_cast<__half2*>(&A2) = __hfma2(up[2], a, *reinterpret_cast<__half2*>(&A2));
    *reinterpret_cast<__half2*>(&A3) = __hfma2(up[3], a, *reinterpret_cast<__half2*>(&A3));
}

// ============================================================================
// R22: xp = h @ W2 via MFMA 16x16x32 f16. 64 nodes/block, 4 waves; wave owns
// 16 rows x 128 cols = 8 C-tiles (16 MFMA). A-frag: lane&15=row, (lane>>4)*8
// =k-slice -> one uint4 straight from fp16 h. B from W2t fp16 [col][k].
// C/D layout (m89-verified): col=lane&15, row=(lane>>4)*4+j.
// Attention dots from f32 acc in-register; xph stored via LDS transpose.
// ============================================================================
__global__ __launch_bounds__(256)
void k_xp_gemm64h(const __half* __restrict__ x, const _Float16* __restrict__ W2t,
                  const float* __restrict__ as_, const float* __restrict__ ad_,
                  __half* __restrict__ xph, float* __restrict__ asrc,
                  float* __restrict__ adst, int N) {
    __shared__ __half lh[4][16][128];       // 16 KB
    const int t = threadIdx.x;
    const int w = t >> 6, lane = t & 63;
    const int c8 = lane & 15, kgrp = lane >> 4;
    const int nr0 = blockIdx.x * 64 + w * 16;

    // A fragments (k 0..31 and 32..63 for this lane's row)
    uint4 a0u = make_uint4(0u,0u,0u,0u), a1u = make_uint4(0u,0u,0u,0u);
    int ar = nr0 + c8;
    if (ar < N) {
        const uint4* hp = (const uint4*)(x + (size_t)ar * 64);
        a0u = hp[kgrp];
        a1u = hp[4 + kgrp];
    }
    half8 A0, A1;
    __builtin_memcpy(&A0, &a0u, 16);
    __builtin_memcpy(&A1, &a1u, 16);

    f32x4 acc[8];
    #pragma unroll
    for (int i = 0; i < 8; ++i) acc[i] = (f32x4){0.f, 0.f, 0.f, 0.f};

    #pragma unroll
    for (int ct = 0; ct < 8; ++ct) {
        const uint4* wp = (const uint4*)(W2t + (size_t)(ct * 16 + c8) * 64);
        uint4 b0u = wp[kgrp];
        uint4 b1u = wp[4 + kgrp];
        half8 B0, B1;
        __builtin_memcpy(&B0, &b0u, 16);
        __builtin_memcpy(&B1, &b1u, 16);
        acc[ct] = __builtin_amdgcn_mfma_f32_16x16x32_f16(A0, B0, acc[ct], 0, 0, 0);
        acc[ct] = __builtin_amdgcn_mfma_f32_16x16x32_f16(A1, B1, acc[ct], 0, 0, 0);
    }

    // attention dots (per row j): head0 = ct 0..3, head1 = ct 4..7
    float ps0[4] = {0,0,0,0}, ps1[4] = {0,0,0,0};
    float pd0[4] = {0,0,0,0}, pd1[4] = {0,0,0,0};
    #pragma unroll
    for (int ct = 0; ct < 8; ++ct) {
        float av = as_[ct * 16 + c8];
        float dv = ad_[ct * 16 + c8];
        #pragma unroll
        for (int j = 0; j < 4; ++j) {
            float v = acc[ct][j];
            if (ct < 4) { ps0[j] += av * v; pd0[j] += dv * v; }
            else        { ps1[j] += av * v; pd1[j] += dv * v; }
        }
    }
    #pragma unroll
    for (int off = 1; off <= 8; off <<= 1) {
        #pragma unroll
        for (int j = 0; j < 4; ++j) {
            ps0[j] += __shfl_xor(ps0[j], off, 64);
            ps1[j] += __shfl_xor(ps1[j], off, 64);
            pd0[j] += __shfl_xor(pd0[j], off, 64);
            pd1[j] += __shfl_xor(pd1[j], off, 64);
        }
    }
    if (c8 == 0) {
        #pragma unroll
        for (int j = 0; j < 4; ++j) {
            int gn = nr0 + kgrp * 4 + j;
            if (gn < N) {
                asrc[gn * 2]     = ps0[j];
                asrc[gn * 2 + 1] = ps1[j];
                adst[gn * 2]     = pd0[j];
                adst[gn * 2 + 1] = pd1[j];
            }
        }
    }

    // xph store: stage C tile in LDS (fp16), then coalesced uint4 rows
    #pragma unroll
    for (int ct = 0; ct < 8; ++ct)
        #pragma unroll
        for (int j = 0; j < 4; ++j)
            lh[w][kgrp * 4 + j][ct * 16 + c8] = __float2half(acc[ct][j]);
    __syncthreads();
    {
        int r = lane >> 2, q = lane & 3;
        int gn = nr0 + r;
        if (gn < N) {
            const uint4* srow = (const uint4*)&lh[w][r][0];
            uint4* drow = (uint4*)(xph + (size_t)gn * 128);
            #pragma unroll
            for (int c4 = 0; c4 < 4; ++c4) drow[q * 4 + c4] = srow[q * 4 + c4];
        }
    }
}

// ============================================================================
// R21 CSR BUILD via bucket radix partition (R22: ebuf packed u32 = src<<9|loc)
// ============================================================================
__global__ __launch_bounds__(256)
void k_bcount(const int* __restrict__ dst, int* __restrict__ bkt_cnt, int E, int nb) {
    __shared__ int cnt[MAXB];
    int t = threadIdx.x;
    for (int i = t; i < MAXB; i += 256) cnt[i] = 0;
    __syncthreads();
    int be = blockIdx.x * 4096;
    int n = min(4096, E - be);
    const int4* d4 = (const int4*)(dst + be);
    #pragma unroll
    for (int i = 0; i < 4; ++i) {
        int j = t + 256 * i, r = j * 4;
        if (r < n) {
            int4 d = d4[j];
            if (r + 0 < n) atomicAdd(&cnt[d.x >> BKSH], 1);
            if (r + 1 < n) atomicAdd(&cnt[d.y >> BKSH], 1);
            if (r + 2 < n) atomicAdd(&cnt[d.z >> BKSH], 1);
            if (r + 3 < n) atomicAdd(&cnt[d.w >> BKSH], 1);
        }
    }
    __syncthreads();
    for (int b = t; b < nb; b += 256) if (cnt[b]) atomicAdd(&bkt_cnt[b], cnt[b]);
}

// block 0: bucket scan; block 1: W2 (64x128 f32) -> W2t (128x64 fp16)
__global__ __launch_bounds__(256)
void k_bscan_prep(const int* __restrict__ bkt_cnt, int* __restrict__ bkt_base,
                  int* __restrict__ bkt_cur, int nb, int E,
                  const float* __restrict__ W2, _Float16* __restrict__ W2t) {
    int t = threadIdx.x;
    if (blockIdx.x == 1) {
        for (int i = t; i < 128 * 64; i += 256) {
            int c = i >> 6, k = i & 63;
            W2t[i] = (_Float16)W2[k * 128 + c];
        }
        return;
    }
    __shared__ int sh[256];
    int v = (t < nb) ? bkt_cnt[t] : 0;
    int orig = v;
    sh[t] = v; __syncthreads();
    for (int off = 1; off < 256; off <<= 1) {
        int u = (t >= off) ? sh[t - off] : 0;
        __syncthreads(); sh[t] += u; __syncthreads();
    }
    int base = sh[t] - orig;
    if (t < nb) { bkt_base[t] = base; bkt_cur[t] = base; }
    if (t == 0) bkt_base[nb] = E;
}

__global__ __launch_bounds__(256)
void k_part(const int* __restrict__ src, const int* __restrict__ dst,
            int* __restrict__ bkt_cur, unsigned* __restrict__ ebuf, int E) {
    __shared__ int cnt[MAXB];
    __shared__ int shift[MAXB];
    __shared__ int cur[MAXB];
    __shared__ int sh[256];
    __shared__ unsigned data[4096];
    __shared__ unsigned char bof[4096];
    int t = threadIdx.x;
    cnt[t] = 0;
    __syncthreads();
    int be = blockIdx.x * 4096;
    int n = min(4096, E - be);
    const int4* d4 = (const int4*)(dst + be);
    const int4* s4 = (const int4*)(src + be);
    #pragma unroll
    for (int i = 0; i < 4; ++i) {
        int j = t + 256 * i, r = j * 4;
        if (r < n) {
            int4 d = d4[j];
            if (r + 0 < n) atomicAdd(&cnt[d.x >> BKSH], 1);
            if (r + 1 < n) atomicAdd(&cnt[d.y >> BKSH], 1);
            if (r + 2 < n) atomicAdd(&cnt[d.z >> BKSH], 1);
            if (r + 3 < n) atomicAdd(&cnt[d.w >> BKSH], 1);
        }
    }
    __syncthreads();
    int v = cnt[t], orig = v;
    sh[t] = v; __syncthreads();
    for (int off = 1; off < 256; off <<= 1) {
        int u = (t >= off) ? sh[t - off] : 0;
        __syncthreads(); sh[t] += u; __syncthreads();
    }
    int lb = sh[t] - orig;
    cur[t] = lb;
    if (orig > 0) {
        int g = atomicAdd(&bkt_cur[t], orig);
        shift[t] = g - lb;
    }
    __syncthreads();
    #pragma unroll
    for (int i = 0; i < 4; ++i) {
        int j = t + 256 * i, r = j * 4;
        if (r < n) {
            int4 d = d4[j]; int4 s = s4[j];
            if (r + 0 < n) { int b = d.x >> BKSH; int p = atomicAdd(&cur[b], 1); data[p] = ((unsigned)s.x << BKSH) | (unsigned)(d.x & (BKW-1)); bof[p] = (unsigned char)b; }
            if (r + 1 < n) { int b = d.y >> BKSH; int p = atomicAdd(&cur[b], 1); data[p] = ((unsigned)s.y << BKSH) | (unsigned)(d.y & (BKW-1)); bof[p] = (unsigned char)b; }
            if (r + 2 < n) { int b = d.z >> BKSH; int p = atomicAdd(&cur[b], 1); data[p] = ((unsigned)s.z << BKSH) | (unsigned)(d.z & (BKW-1)); bof[p] = (unsigned char)b; }
            if (r + 3 < n) { int b = d.w >> BKSH; int p = atomicAdd(&cur[b], 1); data[p] = ((unsigned)s.w << BKSH) | (unsigned)(d.w & (BKW-1)); bof[p] = (unsigned char)b; }
        }
    }
    __syncthreads();
    for (int j = t; j < n; j += 256) {
        int b = bof[j];
        ebuf[shift[b] + j] = data[j];
    }
}

// ============================================================================
// k_build (+ gemm6 + climber fused, branched on blockIdx)
// ============================================================================
__global__ __launch_bounds__(256)
void k_build(const unsigned* __restrict__ ebuf, const int* __restrict__ bkt_base,
             int* __restrict__ rowptr, int* __restrict__ csr_src, int N, int E, int nb,
             const float* __restrict__ x, const float* __restrict__ W1,
             const float* __restrict__ as1, const float* __restrict__ ad1,
             __half* __restrict__ xph, float* __restrict__ asrc,
             float* __restrict__ adst,
             const float* __restrict__ climber, const float* __restrict__ Wc,
             const float* __restrict__ bc, const float* __restrict__ Wm1,
             const float* __restrict__ bm1, float* __restrict__ cpre, int G,
             int nTile) {
    __shared__ char smem[17408];
    __shared__ int sh[256];
    int bid = blockIdx.x;
    const int t = threadIdx.x;

    if (bid < nb) {
        int* deg = (int*)smem;          // 512
        int* pre = deg + 512;           // 512
        int* cur = pre + 512;           // 512
        int n0 = bid << BKSH;
        int nn = min(BKW, N - n0);
        int eb = bkt_base[bid], ee = bkt_base[bid + 1];
        for (int i = t; i < BKW; i += 256) deg[i] = 0;
        __syncthreads();
        for (int j = eb + t; j < ee; j += 256)
            atomicAdd(&deg[ebuf[j] & (BKW - 1)], 1);
        __syncthreads();
        int a = deg[2 * t], b2 = deg[2 * t + 1];
        int s = a + b2, orig = s;
        sh[t] = s; __syncthreads();
        for (int off = 1; off < 256; off <<= 1) {
            int u = (t >= off) ? sh[t - off] : 0;
            __syncthreads(); sh[t] += u; __syncthreads();
        }
        int base = sh[t] - orig;
        pre[2 * t] = base; pre[2 * t + 1] = base + a;
        cur[2 * t] = base; cur[2 * t + 1] = base + a;
        __syncthreads();
        for (int i = t; i < nn; i += 256) rowptr[n0 + i] = eb + pre[i];
        for (int j = eb + t; j < ee; j += 256) {
            unsigned e = ebuf[j];
            int lp = atomicAdd(&cur[e & (BKW - 1)], 1);
            csr_src[eb + lp] = (int)(e >> BKSH);
        }
        if (bid == 0 && t == 0) rowptr[N] = E;
        return;
    }
    bid -= nb;
    if (bid < nTile) {
        constexpr int K = 6, ZS = 7;
        float* smf = (float*)smem;
        float* zs = smf;
        float* ws = smf + 448;
        const int n0 = bid * 64;

        for (int i = t; i < K * 32; i += 256) ((float4*)ws)[i] = ((const float4*)W1)[i];
        for (int i = t; i < 64 * K; i += 256) {
            int n = i / K, k = i - n * K;
            int gn = n0 + n;
            zs[n * ZS + k] = (gn < N) ? x[(size_t)gn * K + k] : 0.f;
        }
        __syncthreads();

        const int tx = t & 15, ty = t >> 4;
        const int c0a = tx * 4;
        const int c0b = 64 + tx * 4;

        float4 asA = *(const float4*)(as1 + c0a);
        float4 asB = *(const float4*)(as1 + c0b);
        float4 adA = *(const float4*)(ad1 + c0a);
        float4 adB = *(const float4*)(ad1 + c0b);

        float acc[4][8];
        #pragma unroll
        for (int i = 0; i < 4; ++i)
            #pragma unroll
            for (int j = 0; j < 8; ++j) acc[i][j] = 0.f;

        for (int k = 0; k < K; ++k) {
            float4 w0 = *(const float4*)(ws + k * 128 + c0a);
            float4 w1 = *(const float4*)(ws + k * 128 + c0b);
            #pragma unroll
            for (int i = 0; i < 4; ++i) {
                float zv = zs[(ty * 4 + i) * ZS + k];
                acc[i][0] += zv * w0.x; acc[i][1] += zv * w0.y;
                acc[i][2] += zv * w0.z; acc[i][3] += zv * w0.w;
                acc[i][4] += zv * w1.x; acc[i][5] += zv * w1.y;
                acc[i][6] += zv * w1.z; acc[i][7] += zv * w1.w;
            }
        }

        #pragma unroll
        for (int i = 0; i < 4; ++i) {
            int nl = ty * 4 + i, gn = n0 + nl;
            if (gn < N) {
                uint2 ua, ub;
                ua.x = pack2(acc[i][0], acc[i][1]);
                ua.y = pack2(acc[i][2], acc[i][3]);
                ub.x = pack2(acc[i][4], acc[i][5]);
                ub.y = pack2(acc[i][6], acc[i][7]);
                *(uint2*)(xph + (size_t)gn * 128 + c0a) = ua;
                *(uint2*)(xph + (size_t)gn * 128 + c0b) = ub;
            }
            float ps0 = acc[i][0]*asA.x + acc[i][1]*asA.y + acc[i][2]*asA.z + acc[i][3]*asA.w;
            float ps1 = acc[i][4]*asB.x + acc[i][5]*asB.y + acc[i][6]*asB.z + acc[i][7]*asB.w;
            float pd0 = acc[i][0]*adA.x + acc[i][1]*adA.y + acc[i][2]*adA.z + acc[i][3]*adA.w;
            float pd1 = acc[i][4]*adB.x + acc[i][5]*adB.y + acc[i][6]*adB.z + acc[i][7]*adB.w;
            #pragma unroll
            for (int off = 1; off <= 8; off <<= 1) {
                ps0 += __shfl_xor(ps0, off, 64);
                ps1 += __shfl_xor(ps1, off, 64);
                pd0 += __shfl_xor(pd0, off, 64);
                pd1 += __shfl_xor(pd1, off, 64);
            }
            if (tx == 0 && gn < N) {
                asrc[gn * 2]     = ps0;
                asrc[gn * 2 + 1] = ps1;
                adst[gn * 2]     = pd0;
                adst[gn * 2 + 1] = pd1;
            }
        }
        return;
    }
    bid -= nTile;
    {
        float* smf = (float*)smem;
        float* ce   = smf;
        float* wm1b = smf + 256;
        for (int i = t; i < 1024; i += 256) ((float4*)wm1b)[i] = ((const float4*)Wm1)[1024 + i];
        int gl = t >> 6, c = t & 63;
        int g = bid * 4 + gl;
        float acc = bc[c];
        if (g < G)
            for (int k = 0; k < 4; ++k) acc += climber[g * 4 + k] * Wc[k * 64 + c];
        ce[gl * 64 + c] = fmaxf(acc, 0.f);
        __syncthreads();
        float o = bm1[c];
        for (int k = 0; k < 64; ++k) o += ce[gl * 64 + k] * wm1b[k * 64 + c];
        if (g < G) cpre[(size_t)g * 64 + c] = o;
    }
}

// ============================================================================
// FUSED softmax + gather (R1 structure, strided node walk; pk8 R20).
// NOTE (R14): do NOT fuse the classifier MLP in here (occupancy collapse).
// NOTE (R16): do NOT switch to contiguous chunks + deep pipeline (56->76us).
// NOTE (R4): write-byte cuts don't speed this kernel; it is gather/issue-bound.
// ============================================================================
__global__ void k_ag(const int* __restrict__ rowptr, const int* __restrict__ csr_src,
                     const float* __restrict__ asrc, const float* __restrict__ adst,
                     const __half* __restrict__ xph, const float* __restrict__ b,
                     __half* __restrict__ hout, int N) {
    int tid = blockIdx.x * blockDim.x + threadIdx.x;
    int lane = threadIdx.x & 63;
    int wid = tid >> 6;
    int nw = (gridDim.x * blockDim.x) >> 6;
    const int l  = lane & 31;
    const int hh = lane >> 5;
    const int g4 = (lane >> 3) & 3;
    const int c8 = lane & 7;
    const int lofs = hh * 8 + c8;
    const uint4* xp4 = (const uint4*)xph;
    float4 bb0 = ((const float4*)b)[c8 * 2];
    float4 bb1 = ((const float4*)b)[c8 * 2 + 1];

    for (int n = wid; n < N; n += nw) {
        int rs = rowptr[n], re = rowptr[n + 1], cnt = re - rs;
        uint4 uself = xp4[(size_t)n * 16 + lofs];
        float a_dst = adst[n * 2 + hh];
        float eself = __expf(lrelu(asrc[n * 2 + hh] + a_dst));

        unsigned A0 = 0u, A1 = 0u, A2 = 0u, A3 = 0u;
        float den;

        if (cnt <= 32) {
            float ev = 0.f; int s_reg = n;
            if (l < cnt) {
                s_reg = csr_src[rs + l];
                ev = __expf(lrelu(asrc[s_reg * 2 + hh] + a_dst));
            }
            unsigned evp = pack2(ev, ev);
            if (g4 == 0) pk8(A0, A1, A2, A3, pack2(eself, eself), uself);

            const int base = (hh << 5) - rs;
            int e0 = rs;
            for (; e0 + 4 < re; e0 += 8) {
                int ea = e0 + g4, eb = e0 + 4 + g4;
                unsigned aa = __shfl(evp,   base + ea, 64);
                int      sa = __shfl(s_reg, base + ea, 64);
                unsigned ab = __shfl(evp,   base + eb, 64);
                int      sb = __shfl(s_reg, base + eb, 64);
                if (eb >= re) { ab = 0u; sb = n; }
                uint4 u1 = xp4[(size_t)sa * 16 + lofs];
                uint4 u2 = xp4[(size_t)sb * 16 + lofs];
                pk8(A0, A1, A2, A3, aa, u1);
                pk8(A0, A1, A2, A3, ab, u2);
            }
            if (e0 < re) {
                int ea = e0 + g4;
                unsigned aa = __shfl(evp,   base + ea, 64);
                int      sa = __shfl(s_reg, base + ea, 64);
                if (ea >= re) { aa = 0u; sa = n; }
                uint4 u1 = xp4[(size_t)sa * 16 + lofs];
                pk8(A0, A1, A2, A3, aa, u1);
            }
            den = ev + (l == 0 ? eself : 0.f);
            #pragma unroll
            for (int off = 16; off > 0; off >>= 1) den += __shfl_xor(den, off, 64);
        } else {
            den = (l == 0) ? eself : 0.f;
            for (int e = rs + l; e < re; e += 32)
                den += __expf(lrelu(asrc[csr_src[e] * 2 + hh] + a_dst));
            #pragma unroll
            for (int off = 16; off > 0; off >>= 1) den += __shfl_xor(den, off, 64);
            if (g4 == 0) pk8(A0, A1, A2, A3, pack2(eself, eself), uself);
            for (int e0 = rs; e0 < re; e0 += 8) {
                int ea = e0 + g4, eb = e0 + 4 + g4;
                bool va = ea < re, vb = eb < re;
                int sa = va ? csr_src[ea] : n;
                int sb = vb ? csr_src[eb] : n;
                float fa = va ? __expf(lrelu(asrc[sa * 2 + hh] + a_dst)) : 0.f;
                float fb = vb ? __expf(lrelu(asrc[sb * 2 + hh] + a_dst)) : 0.f;
                unsigned aa = pack2(fa, fa);
                unsigned ab = pack2(fb, fb);
                uint4 u1 = xp4[(size_t)sa * 16 + lofs];
                uint4 u2 = xp4[(size_t)sb * 16 + lofs];
                pk8(A0, A1, A2, A3, aa, u1);
                pk8(A0, A1, A2, A3, ab, u2);
            }
        }

        float inv = 1.f / (den + 1e-16f);

        float2 f0 = h2f(A0), f1 = h2f(A1), f2 = h2f(A2), f3 = h2f(A3);
        float4 accA = make_float4(f0.x, f0.y, f1.x, f1.y);
        float4 accB = make_float4(f2.x, f2.y, f3.x, f3.y);

        #pragma unroll
        for (int off = 8; off <= 16; off <<= 1) {
            accA.x += __shfl_xor(accA.x, off, 64);
            accA.y += __shfl_xor(accA.y, off, 64);
            accA.z += __shfl_xor(accA.z, off, 64);
            accA.w += __shfl_xor(accA.w, off, 64);
            accB.x += __shfl_xor(accB.x, off, 64);
            accB.y += __shfl_xor(accB.y, off, 64);
            accB.z += __shfl_xor(accB.z, off, 64);
            accB.w += __shfl_xor(accB.w, off, 64);
        }
        accA.x *= inv; accA.y *= inv; accA.z *= inv; accA.w *= inv;
        accB.x *= inv; accB.y *= inv; accB.z *= inv; accB.w *= inv;
        accA.x += __shfl_xor(accA.x, 32, 64);
        accA.y += __shfl_xor(accA.y, 32, 64);
        accA.z += __shfl_xor(accA.z, 32, 64);
        accA.w += __shfl_xor(accA.w, 32, 64);
        accB.x += __shfl_xor(accB.x, 32, 64);
        accB.y += __shfl_xor(accB.y, 32, 64);
        accB.z += __shfl_xor(accB.z, 32, 64);
        accB.w += __shfl_xor(accB.w, 32, 64);

        if (lane < 8) {
            uint4 up;
            up.x = pack2(fmaxf(accA.x * 0.5f + bb0.x, 0.f),
                         fmaxf(accA.y * 0.5f + bb0.y, 0.f));
            up.y = pack2(fmaxf(accA.z * 0.5f + bb0.z, 0.f),
                         fmaxf(accA.w * 0.5f + bb0.w, 0.f));
            up.z = pack2(fmaxf(accB.x * 0.5f + bb1.x, 0.f),
                         fmaxf(accB.y * 0.5f + bb1.y, 0.f));
            up.w = pack2(fmaxf(accB.z * 0.5f + bb1.z, 0.f),
                         fmaxf(accB.w * 0.5f + bb1.w, 0.f));
            ((uint4*)hout)[(size_t)n * 8 + c8] = up;
        }
    }
}

// ============================================================================
// Final MLP, block-tile GEMM. h2 fp16. Kept SEPARATE from k_ag (R14).
// ============================================================================
__global__ __launch_bounds__(256)
void k_final(const __half* __restrict__ h2, const float* __restrict__ cpre,
             const int* __restrict__ batch, const float* __restrict__ Wm1,
             const float* __restrict__ Wm2, const float* __restrict__ bm2,
             float* __restrict__ out, int N) {
    __shared__ float zs[64 * 65];
    __shared__ float ws[64 * 64];
    __shared__ float4 w2l[64];
    const int n0 = blockIdx.x * 64;
    const int t = threadIdx.x;

    for (int i = t; i < 1024; i += 256) ((float4*)ws)[i] = ((const float4*)Wm1)[i];
    if (t < 64) w2l[t] = ((const float4*)Wm2)[t];
    for (int i = t; i < 64 * 8; i += 256) {
        int n = i >> 3, k8 = i & 7;
        int gn = n0 + n;
        uint4 v = make_uint4(0u, 0u, 0u, 0u);
        if (gn < N) v = ((const uint4*)h2)[(size_t)gn * 8 + k8];
        float2 f0 = h2f(v.x), f1 = h2f(v.y), f2 = h2f(v.z), f3 = h2f(v.w);
        float* zr = zs + n * 65 + k8 * 8;
        zr[0] = f0.x; zr[1] = f0.y; zr[2] = f1.x; zr[3] = f1.y;
        zr[4] = f2.x; zr[5] = f2.y; zr[6] = f3.x; zr[7] = f3.y;
    }
    __syncthreads();

    const int tx = t & 15, ty = t >> 4;
    const int c0 = tx * 4;
    float acc[4][4];
    #pragma unroll
    for (int i = 0; i < 4; ++i)
        #pragma unroll
        for (int j = 0; j < 4; ++j) acc[i][j] = 0.f;

    for (int k = 0; k < 64; ++k) {
        float4 wv = *(const float4*)(ws + k * 64 + c0);
        #pragma unroll
        for (int i = 0; i < 4; ++i) {
            float zv = zs[(ty * 4 + i) * 65 + k];
            acc[i][0] += zv * wv.x; acc[i][1] += zv * wv.y;
            acc[i][2] += zv * wv.z; acc[i][3] += zv * wv.w;
        }
    }
    __syncthreads();

    float4 wa = w2l[c0], wb = w2l[c0 + 1], wc = w2l[c0 + 2], wd = w2l[c0 + 3];
    #pragma unroll
    for (int i = 0; i < 4; ++i) {
        int nl = ty * 4 + i, gn = n0 + nl;
        float4 o = make_float4(0.f, 0.f, 0.f, 0.f);
        if (gn < N) {
            int b = batch[gn];
            float4 cp = *(const float4*)(cpre + (size_t)b * 64 + c0);
            float m0 = fmaxf(acc[i][0] + cp.x, 0.f);
            float m1 = fmaxf(acc[i][1] + cp.y, 0.f);
            float m2 = fmaxf(acc[i][2] + cp.z, 0.f);
            float m3 = fmaxf(acc[i][3] + cp.w, 0.f);
            o.x = m0 * wa.x + m1 * wb.x + m2 * wc.x + m3 * wd.x;
            o.y = m0 * wa.y + m1 * wb.y + m2 * wc.y + m3 * wd.y;
            o.z = m0 * wa.z + m1 * wb.z + m2 * wc.z + m3 * wd.z;
            o.w = m0 * wa.w + m1 * wb.w + m2 * wc.w + m3 * wd.w;
        }
        *(float4*)(zs + tx * 260 + nl * 4) = o;
    }
    __syncthreads();
    {
        int nl = t >> 2, j = t & 3, gn = n0 + nl;
        float s = 0.f;
        #pragma unroll
        for (int tx2 = 0; tx2 < 16; ++tx2) s += zs[tx2 * 260 + nl * 4 + j];
        if (gn < N) out[(size_t)gn * 4 + j] = s + bm2[j];
    }
}

extern "C" void kernel_launch(void* const* d_in, const int* in_sizes, int n_in,
                              void* d_out, int out_size, void* d_ws, size_t ws_size,
                              hipStream_t stream) {
    const float* x       = (const float*)d_in[0];
    const int*   ei      = (const int*)  d_in[1];
    const int*   batch   = (const int*)  d_in[2];
    const float* climber = (const float*)d_in[3];
    const float* W1  = (const float*)d_in[4];
    const float* as1 = (const float*)d_in[5];
    const float* ad1 = (const float*)d_in[6];
    const float* b1  = (const float*)d_in[7];
    const float* W2  = (const float*)d_in[8];
    const float* as2 = (const float*)d_in[9];
    const float* ad2 = (const float*)d_in[10];
    const float* b2  = (const float*)d_in[11];
    const float* Wc  = (const float*)d_in[12];
    const float* bc  = (const float*)d_in[13];
    const float* Wm1 = (const float*)d_in[14];
    const float* bm1 = (const float*)d_in[15];
    const float* Wm2 = (const float*)d_in[16];
    const float* bm2 = (const float*)d_in[17];

    const int N  = in_sizes[0] / 6;
    const int E  = in_sizes[1] / 2;
    const int G  = in_sizes[3] / 4;

    const int* srcI = ei;
    const int* dstI = ei + E;

    // ---------------- workspace carve ----------------
    char* base = (char*)d_ws;
    size_t off = 0;
    auto carve = [&](size_t bytes) { void* p = base + off; off += (bytes + 255) & ~size_t(255); return p; };
    __half* xph    = (__half*)carve((size_t)N * 128 * 2);
    __half* hbuf   = (__half*)carve((size_t)N * 64 * 2);
    float* asrc    = (float*)carve((size_t)N * 2 * 4);
    float* adst    = (float*)carve((size_t)N * 2 * 4);
    float* cpre    = (float*)carve((size_t)G * 64 * 4);
    int*   rowptr  = (int*)  carve((size_t)(N + 1) * 4);
    int*   csr_src = (int*)  carve((size_t)E * 4);
    unsigned* ebuf = (unsigned*)carve((size_t)E * 4);
    int*   bkt_cnt = (int*)  carve((size_t)MAXB * 4);
    int*   bkt_base= (int*)  carve((size_t)(MAXB + 1) * 4);
    int*   bkt_cur = (int*)  carve((size_t)MAXB * 4);
    _Float16* W2t  = (_Float16*)carve((size_t)128 * 64 * 2);

    const int tpb = 256;
    const int nb = (N + BKW - 1) >> BKSH;
    const int nChunk = (E + 4095) / 4096;
    const int nClimber = (G + 3) / 4;
    const int PG = 2048;
    const int nTile = (N + 63) / 64;

    // ---------------- CSR via bucket radix partition (R21/R22) -------------
    hipMemsetAsync(bkt_cnt, 0, (size_t)nb * 4, stream);
    k_bcount<<<nChunk, tpb, 0, stream>>>(dstI, bkt_cnt, E, nb);
    k_bscan_prep<<<2, tpb, 0, stream>>>(bkt_cnt, bkt_base, bkt_cur, nb, E, W2, W2t);
    k_part<<<nChunk, tpb, 0, stream>>>(srcI, dstI, bkt_cur, ebuf, E);
    k_build<<<nb + nTile + nClimber, tpb, 0, stream>>>(
        ebuf, bkt_base, rowptr, csr_src, N, E, nb,
        x, W1, as1, ad1, xph, asrc, adst,
        climber, Wc, bc, Wm1, bm1, cpre, G, nTile);

    // ---------------- layer 1 aggregate ----------------
    k_ag<<<PG, tpb, 0, stream>>>(rowptr, csr_src, asrc, adst, xph, b1, hbuf, N);

    // ---------------- layer 2 ----------------
    k_xp_gemm64h<<<nTile, tpb, 0, stream>>>(hbuf, W2t, as2, ad2, xph, asrc, adst, N);
    k_ag<<<PG, tpb, 0, stream>>>(rowptr, csr_src, asrc, adst, xph, b2, hbuf, N);

    // ---------------- classifier ----------------
    k_final<<<nTile, tpb, 0, stream>>>(hbuf, cpre, batch, Wm1, Wm2, bm2, (float*)d_out, N);
}